// Round 3
// baseline (1698.457 us; speedup 1.0000x reference)
//
#include <hip/hip_runtime.h>
#include <cmath>

typedef short bfv8 __attribute__((ext_vector_type(8)));   // 8 bf16 as raw shorts
typedef float fv4  __attribute__((ext_vector_type(4)));

#define MFMA_B16(a,b,c) __builtin_amdgcn_mfma_f32_16x16x32_bf16((a),(b),(c),0,0,0)

__device__ __forceinline__ float siluf(float x) { return x / (1.0f + expf(-x)); }

// pack split-bf16: low 16 bits = hi-part bf16, high 16 bits = lo-part bf16
__device__ __forceinline__ unsigned packsplit(float v) {
  unsigned uh = __float_as_uint(v) & 0xffff0000u;
  float lof = v - __uint_as_float(uh);
  return (uh >> 16) | (__float_as_uint(lof) & 0xffff0000u);
}

__device__ __forceinline__ unsigned bf16rne(float x) {
  unsigned u = __float_as_uint(x);
  return (u + 0x7fffu + ((u >> 16) & 1u)) >> 16;
}

// ---------------------------------------------------------------------------
// Sorting pipeline: counting sort of edges by row
// ---------------------------------------------------------------------------
__global__ void hist_kernel(const int* __restrict__ eidx, int E,
                            unsigned* __restrict__ cnt)
{
  const int e = blockIdx.x * 256 + threadIdx.x;
  if (e < E) atomicAdd(&cnt[eidx[e]], 1u);
}

__global__ void scan_kernel(const unsigned* __restrict__ cnt,
                            unsigned* __restrict__ cursor, int N)
{
  __shared__ unsigned part[1024];
  const int t = threadIdx.x;
  const int chunk = (N + 1023) / 1024;
  const int base = t * chunk;
  unsigned s = 0;
  for (int i = 0; i < chunk; ++i) {
    const int idx = base + i;
    if (idx < N) s += cnt[idx];
  }
  part[t] = s;
  __syncthreads();
  for (int off = 1; off < 1024; off <<= 1) {
    unsigned v = 0;
    if (t >= off) v = part[t - off];
    __syncthreads();
    if (t >= off) part[t] += v;
    __syncthreads();
  }
  unsigned pre = (t == 0) ? 0u : part[t - 1];
  for (int i = 0; i < chunk; ++i) {
    const int idx = base + i;
    if (idx < N) { cursor[idx] = pre; pre += cnt[idx]; }
  }
}

__global__ void scatter_kernel(const float* __restrict__ x,
                               const int* __restrict__ eidx,
                               const float* __restrict__ eattr, int E,
                               unsigned* __restrict__ cursor,
                               int* __restrict__ sRowA, int* __restrict__ sColA,
                               float* __restrict__ sRadA, float* __restrict__ sEaA)
{
  const int e = blockIdx.x * 256 + threadIdx.x;
  if (e >= E) return;
  const int r = eidx[e], c = eidx[E + e];
  const float dx = x[(size_t)r * 3 + 0] - x[(size_t)c * 3 + 0];
  const float dy = x[(size_t)r * 3 + 1] - x[(size_t)c * 3 + 1];
  const float dz = x[(size_t)r * 3 + 2] - x[(size_t)c * 3 + 2];
  const unsigned pos = atomicAdd(&cursor[r], 1u);
  sRowA[pos] = r;
  sColA[pos] = c;
  sRadA[pos] = dx * dx + dy * dy + dz * dz;
  sEaA[pos]  = eattr[e];
}

// ---------------------------------------------------------------------------
// Fused edge pipeline (MFMA split-bf16), SORTED edges.
// Block: 256 thr = 4 waves; 128 sorted edges/block; wave owns 32 rows.
// MODE 0: GCL edge model -> LDS stage + segmented reduce -> sparse atomics
// MODE 1: Equivariant    -> atomics into x_out[N,3]
// ---------------------------------------------------------------------------
template <int MODE>
__global__ __launch_bounds__(256, 2)
void edge_mfma(const unsigned short* __restrict__ hhi,
               const unsigned short* __restrict__ hlo,
               const int* __restrict__ sRowA, const int* __restrict__ sColA,
               const float* __restrict__ sRadA, const float* __restrict__ sEaA,
               int E,
               const unsigned short* __restrict__ w1h, const unsigned short* __restrict__ w1l,
               const float* __restrict__ W1full, const float* __restrict__ b1,
               const unsigned short* __restrict__ w2h, const unsigned short* __restrict__ w2l,
               const float* __restrict__ b2,
               const float* __restrict__ awv, const float* __restrict__ abv,
               const float* __restrict__ xin,
               float* __restrict__ outbuf)
{
  extern __shared__ __align__(16) char smem[];
  unsigned* sHall  = (unsigned*)smem;                       // 4 x 2048 u32 (32KB)
  unsigned* sStage = (unsigned*)(smem + 32768);             // MODE0: 128x64 u32 (32KB)
  char* ebase = smem + (MODE == 0 ? 65536 : 32768);
  int*   sRow = (int*)ebase;
  int*   sCol = sRow + 128;
  float* sRad = (float*)(sCol + 128);
  float* sEa  = sRad + 128;

  const int tid = threadIdx.x;
  const int w = tid >> 6, l = tid & 63;
  const int c16 = l & 15, g = l >> 4;
  const int e0 = blockIdx.x * 128;

  if (tid < 128) {
    const int e = min(e0 + tid, E - 1);
    sRow[tid] = sRowA[e];
    sCol[tid] = sColA[e];
    sRad[tid] = sRadA[e];
    sEa[tid]  = sEaA[e];
  }
  __syncthreads();

  const int rw = w * 32;
  int nidA[2], nidB[2];
#pragma unroll
  for (int rt = 0; rt < 2; ++rt) {
    nidA[rt] = sRow[rw + rt * 16 + c16];
    nidB[rt] = sCol[rw + rt * 16 + c16];
  }

  fv4 acc[2][8];
#pragma unroll
  for (int a = 0; a < 2; ++a)
#pragma unroll
    for (int b = 0; b < 8; ++b) acc[a][b] = (fv4)0.0f;

  // ---- GEMM1: [32 x 256] x W1^T (k 0..127 = h[row], 128..255 = h[col]) ----
#pragma unroll 2
  for (int kc = 0; kc < 8; ++kc) {
    bfv8 Ah[2], Al[2];
    const int kh = (kc & 3) * 32 + g * 8;
#pragma unroll
    for (int rt = 0; rt < 2; ++rt) {
      const int nid = (kc < 4) ? nidA[rt] : nidB[rt];
      const size_t off = (size_t)nid * 128 + kh;
      Ah[rt] = *(const bfv8*)(hhi + off);
      Al[rt] = *(const bfv8*)(hlo + off);
    }
#pragma unroll
    for (int jt = 0; jt < 8; ++jt) {
      const size_t bo = ((size_t)(kc * 8 + jt) * 64 + l) * 8;
      bfv8 Bh = *(const bfv8*)(w1h + bo);
      bfv8 Bl = *(const bfv8*)(w1l + bo);
#pragma unroll
      for (int rt = 0; rt < 2; ++rt) {
        acc[rt][jt] = MFMA_B16(Ah[rt], Bh, acc[rt][jt]);
        acc[rt][jt] = MFMA_B16(Al[rt], Bh, acc[rt][jt]);
        acc[rt][jt] = MFMA_B16(Ah[rt], Bl, acc[rt][jt]);
      }
    }
  }

  unsigned* sHW = sHall + w * 2048;
  const float ab0 = (MODE == 0) ? abv[0] : 0.0f;

#pragma unroll 1
  for (int rt = 0; rt < 2; ++rt) {
    // ---- epilogue1: tail cols (radial, ea) + bias + silu -> sH (swizzled) ----
#pragma unroll
    for (int jt = 0; jt < 8; ++jt) {
      const int col = jt * 16 + c16;
      const float wt0 = W1full[(size_t)col * 258 + 256];
      const float wt1 = W1full[(size_t)col * 258 + 257];
      const float bb  = b1[col];
#pragma unroll
      for (int reg = 0; reg < 4; ++reg) {
        const int rr = 4 * g + reg;
        const int er = rw + rt * 16 + rr;
        const float v = acc[rt][jt][reg] + sRad[er] * wt0 + sEa[er] * wt1 + bb;
        sHW[rr * 128 + (col ^ ((rr & 7) << 2))] = packsplit(siluf(v));
      }
    }

    // ---- GEMM2: silu(H1)[16x128] x W2^T ----
    fv4 accB[8];
#pragma unroll
    for (int jt = 0; jt < 8; ++jt) accB[jt] = (fv4)0.0f;
    const int sxz = (c16 & 7) << 2;
#pragma unroll 2
    for (int kc2 = 0; kc2 < 4; ++kc2) {
      const int k0 = kc2 * 32 + g * 8;
      const int i1 = c16 * 128 + (k0 ^ sxz);
      const int4 q0 = *((const int4*)(sHW + i1));
      const int4 q1 = *((const int4*)(sHW + (i1 ^ 4)));
      bfv8 Ah2, Al2;
      {
        const int qq[8] = {q0.x, q0.y, q0.z, q0.w, q1.x, q1.y, q1.z, q1.w};
#pragma unroll
        for (int i = 0; i < 8; ++i) {
          Ah2[i] = (short)(((unsigned)qq[i]) & 0xffffu);
          Al2[i] = (short)(((unsigned)qq[i]) >> 16);
        }
      }
#pragma unroll
      for (int jt = 0; jt < 8; ++jt) {
        const size_t bo = ((size_t)(kc2 * 8 + jt) * 64 + l) * 8;
        bfv8 Bh = *(const bfv8*)(w2h + bo);
        bfv8 Bl = *(const bfv8*)(w2l + bo);
        accB[jt] = MFMA_B16(Ah2, Bh, accB[jt]);
        accB[jt] = MFMA_B16(Al2, Bh, accB[jt]);
        accB[jt] = MFMA_B16(Ah2, Bl, accB[jt]);
      }
    }

    // ---- epilogue2 ----
    float p[4] = {0.f, 0.f, 0.f, 0.f};
#pragma unroll
    for (int jt = 0; jt < 8; ++jt) {
      const int col = jt * 16 + c16;
      const float bb = b2[col], aa = awv[col];
#pragma unroll
      for (int reg = 0; reg < 4; ++reg) {
        const float m = siluf(accB[jt][reg] + bb);
        accB[jt][reg] = m;
        p[reg] += m * aa;
      }
    }
#pragma unroll
    for (int msk = 1; msk < 16; msk <<= 1) {
#pragma unroll
      for (int reg = 0; reg < 4; ++reg) p[reg] += __shfl_xor(p[reg], msk, 64);
    }

    if constexpr (MODE == 0) {
      // stage mij*att as packed bf16 col-pairs into sStage (swizzled)
      float att[4];
#pragma unroll
      for (int reg = 0; reg < 4; ++reg)
        att[reg] = 1.0f / (1.0f + expf(-(p[reg] + ab0)));
#pragma unroll
      for (int jt = 0; jt < 8; ++jt) {
#pragma unroll
        for (int reg = 0; reg < 4; ++reg) {
          const int er = rw + rt * 16 + 4 * g + reg;
          float v = (e0 + er < E) ? accB[jt][reg] * att[reg] : 0.0f;
          const float vn = __shfl_xor(v, 1, 64);
          if (!(c16 & 1)) {
            const int cp = jt * 8 + (c16 >> 1);
            sStage[er * 64 + (cp ^ (((er >> 2) & 3) << 3))] =
                bf16rne(v) | (bf16rne(vn) << 16);
          }
        }
      }
    } else {
      if (c16 == 0) {
#pragma unroll
        for (int reg = 0; reg < 4; ++reg) {
          const int er = rw + rt * 16 + 4 * g + reg;
          const int e = e0 + er;
          if (e < E) {
            const float s = p[reg] * 0.01f;          // / NORM_FACTOR
            const int nr = sRow[er], nc = sCol[er];
            const float dx = xin[(size_t)nr * 3 + 0] - xin[(size_t)nc * 3 + 0];
            const float dy = xin[(size_t)nr * 3 + 1] - xin[(size_t)nc * 3 + 1];
            const float dz = xin[(size_t)nr * 3 + 2] - xin[(size_t)nc * 3 + 2];
            const float inv = 1.0f / (sqrtf(dx * dx + dy * dy + dz * dz + 1e-8f) + 1.0f);
            unsafeAtomicAdd(outbuf + (size_t)nr * 3 + 0, dx * inv * s);
            unsafeAtomicAdd(outbuf + (size_t)nr * 3 + 1, dy * inv * s);
            unsafeAtomicAdd(outbuf + (size_t)nr * 3 + 2, dz * inv * s);
          }
        }
      }
    }
  }

  if constexpr (MODE == 0) {
    __syncthreads();
    // segmented reduction over sorted rows: thread (cp, q) scans 32 rows
    const int cp = tid & 63;
    const int q  = tid >> 6;
    const int erb = q * 32;
    float a0 = 0.0f, a1 = 0.0f;
    int cur = sRow[erb];
#pragma unroll 4
    for (int i = 0; i < 32; ++i) {
      const int er = erb + i;
      const int r = sRow[er];
      if (r != cur) {
        if (a0 != 0.0f || a1 != 0.0f) {
          unsafeAtomicAdd(outbuf + (size_t)cur * 128 + 2 * cp,     a0);
          unsafeAtomicAdd(outbuf + (size_t)cur * 128 + 2 * cp + 1, a1);
        }
        cur = r; a0 = 0.0f; a1 = 0.0f;
      }
      const unsigned u = sStage[er * 64 + (cp ^ (((er >> 2) & 3) << 3))];
      a0 += __uint_as_float(u << 16);
      a1 += __uint_as_float(u & 0xffff0000u);
    }
    if (a0 != 0.0f || a1 != 0.0f) {
      unsafeAtomicAdd(outbuf + (size_t)cur * 128 + 2 * cp,     a0);
      unsafeAtomicAdd(outbuf + (size_t)cur * 128 + 2 * cp + 1, a1);
    }
  }
}

// ---------------------------------------------------------------------------
// Node model (MFMA): msg = silu([h, agg/100] W1^T + b1) W2^T + b2; h += msg
// ---------------------------------------------------------------------------
__global__ __launch_bounds__(256, 3)
void node_mfma(float* __restrict__ hio,
               const unsigned short* __restrict__ hhi,
               const unsigned short* __restrict__ hlo,
               const float* __restrict__ agg, int N,
               const unsigned short* __restrict__ w1h, const unsigned short* __restrict__ w1l,
               const float* __restrict__ b1,
               const unsigned short* __restrict__ w2h, const unsigned short* __restrict__ w2l,
               const float* __restrict__ b2)
{
  __shared__ __align__(16) unsigned sH[4][2048];

  const int tid = threadIdx.x;
  const int w = tid >> 6, l = tid & 63;
  const int c16 = l & 15, g = l >> 4;
  const int n0 = blockIdx.x * 128;
  const int rw = w * 32;

  int rowA[2];
#pragma unroll
  for (int rt = 0; rt < 2; ++rt) rowA[rt] = min(n0 + rw + rt * 16 + c16, N - 1);

  fv4 acc[2][8];
#pragma unroll
  for (int a = 0; a < 2; ++a)
#pragma unroll
    for (int b = 0; b < 8; ++b) acc[a][b] = (fv4)0.0f;

#pragma unroll 2
  for (int kc = 0; kc < 8; ++kc) {
    bfv8 Ah[2], Al[2];
    if (kc < 4) {
      const int kh = kc * 32 + g * 8;
#pragma unroll
      for (int rt = 0; rt < 2; ++rt) {
        const size_t off = (size_t)rowA[rt] * 128 + kh;
        Ah[rt] = *(const bfv8*)(hhi + off);
        Al[rt] = *(const bfv8*)(hlo + off);
      }
    } else {
      const int kh = (kc - 4) * 32 + g * 8;
#pragma unroll
      for (int rt = 0; rt < 2; ++rt) {
        const float4 v0 = *(const float4*)(agg + (size_t)rowA[rt] * 128 + kh);
        const float4 v1 = *(const float4*)(agg + (size_t)rowA[rt] * 128 + kh + 4);
        const float vv[8] = {v0.x, v0.y, v0.z, v0.w, v1.x, v1.y, v1.z, v1.w};
#pragma unroll
        for (int i = 0; i < 8; ++i) {
          const float xs = vv[i] * 0.01f;            // agg / normalization_factor
          const unsigned uh = __float_as_uint(xs) & 0xffff0000u;
          Ah[rt][i] = (short)(uh >> 16);
          const float lof = xs - __uint_as_float(uh);
          Al[rt][i] = (short)(__float_as_uint(lof) >> 16);
        }
      }
    }
#pragma unroll
    for (int jt = 0; jt < 8; ++jt) {
      const size_t bo = ((size_t)(kc * 8 + jt) * 64 + l) * 8;
      bfv8 Bh = *(const bfv8*)(w1h + bo);
      bfv8 Bl = *(const bfv8*)(w1l + bo);
#pragma unroll
      for (int rt = 0; rt < 2; ++rt) {
        acc[rt][jt] = MFMA_B16(Ah[rt], Bh, acc[rt][jt]);
        acc[rt][jt] = MFMA_B16(Al[rt], Bh, acc[rt][jt]);
        acc[rt][jt] = MFMA_B16(Ah[rt], Bl, acc[rt][jt]);
      }
    }
  }

  unsigned* sHW = sH[w];
#pragma unroll 1
  for (int rt = 0; rt < 2; ++rt) {
#pragma unroll
    for (int jt = 0; jt < 8; ++jt) {
      const int col = jt * 16 + c16;
      const float bb = b1[col];
#pragma unroll
      for (int reg = 0; reg < 4; ++reg) {
        const int rr = 4 * g + reg;
        sHW[rr * 128 + (col ^ ((rr & 7) << 2))] = packsplit(siluf(acc[rt][jt][reg] + bb));
      }
    }

    fv4 accB[8];
#pragma unroll
    for (int jt = 0; jt < 8; ++jt) accB[jt] = (fv4)0.0f;
    const int sxz = (c16 & 7) << 2;
#pragma unroll 2
    for (int kc2 = 0; kc2 < 4; ++kc2) {
      const int k0 = kc2 * 32 + g * 8;
      const int i1 = c16 * 128 + (k0 ^ sxz);
      const int4 q0 = *((const int4*)(sHW + i1));
      const int4 q1 = *((const int4*)(sHW + (i1 ^ 4)));
      bfv8 Ah2, Al2;
      {
        const int qq[8] = {q0.x, q0.y, q0.z, q0.w, q1.x, q1.y, q1.z, q1.w};
#pragma unroll
        for (int i = 0; i < 8; ++i) {
          Ah2[i] = (short)(((unsigned)qq[i]) & 0xffffu);
          Al2[i] = (short)(((unsigned)qq[i]) >> 16);
        }
      }
#pragma unroll
      for (int jt = 0; jt < 8; ++jt) {
        const size_t bo = ((size_t)(kc2 * 8 + jt) * 64 + l) * 8;
        bfv8 Bh = *(const bfv8*)(w2h + bo);
        bfv8 Bl = *(const bfv8*)(w2l + bo);
        accB[jt] = MFMA_B16(Ah2, Bh, accB[jt]);
        accB[jt] = MFMA_B16(Al2, Bh, accB[jt]);
        accB[jt] = MFMA_B16(Ah2, Bl, accB[jt]);
      }
    }

#pragma unroll
    for (int reg = 0; reg < 4; ++reg) {
      const int n = n0 + rw + rt * 16 + 4 * g + reg;
      if (n < N) {
        float* hp = hio + (size_t)n * 128;
#pragma unroll
        for (int jt = 0; jt < 8; ++jt) {
          const int col = jt * 16 + c16;
          hp[col] += accB[jt][reg] + b2[col];        // residual add
        }
      }
    }
  }
}

// split fp32 -> bf16 hi/lo planes (row-major [N,128])
__global__ void split_kernel(const float* __restrict__ src,
                             unsigned short* __restrict__ hi,
                             unsigned short* __restrict__ lo, int n4)
{
  const int i = blockIdx.x * 256 + threadIdx.x;
  if (i >= n4) return;
  const float4 v = ((const float4*)src)[i];
  const float vv[4] = {v.x, v.y, v.z, v.w};
  ushort4 ho, lq;
  unsigned short* hp = (unsigned short*)&ho;
  unsigned short* lp = (unsigned short*)&lq;
#pragma unroll
  for (int k = 0; k < 4; ++k) {
    const unsigned uh = __float_as_uint(vv[k]) & 0xffff0000u;
    hp[k] = (unsigned short)(uh >> 16);
    const float lof = vv[k] - __uint_as_float(uh);
    lp[k] = (unsigned short)(__float_as_uint(lof) >> 16);
  }
  ((ushort4*)hi)[i] = ho;
  ((ushort4*)lo)[i] = lq;
}

// weight prep: W[j][k] (row-major, stride SW) -> MFMA B-frag layout hi/lo planes
struct WDesc { const float* src; unsigned short* hi; unsigned short* lo; int K; int SW; };
struct WAll { WDesc m[10]; };

__global__ void wprep_kernel(WAll wa)
{
  const WDesc d = wa.m[blockIdx.y];
  const int idx = blockIdx.x * 256 + threadIdx.x;
  const int j = idx & 127, k = idx >> 7;
  if (k >= d.K) return;
  const float v = d.src[(size_t)j * d.SW + k];
  const unsigned uh = __float_as_uint(v) & 0xffff0000u;
  const float lof = v - __uint_as_float(uh);
  // frag index: [ktile][jtile][lane=g*16+c][8]
  const int fo = ((((k >> 5) * 8 + (j >> 4)) * 64) + ((k >> 3) & 3) * 16 + (j & 15)) * 8 + (k & 7);
  d.hi[fo] = (unsigned short)(uh >> 16);
  d.lo[fo] = (unsigned short)(__float_as_uint(lof) >> 16);
}

extern "C" void kernel_launch(void* const* d_in, const int* in_sizes, int n_in,
                              void* d_out, int out_size, void* d_ws, size_t ws_size,
                              hipStream_t stream)
{
  const float* h_in  = (const float*)d_in[0];
  const float* x_in  = (const float*)d_in[1];
  const float* eattr = (const float*)d_in[2];
  const int*   eidx  = (const int*)d_in[3];
  const int N = in_sizes[0] / 128;
  const int E = in_sizes[2];

  const float* P[25];
  for (int i = 0; i < 25; ++i) P[i] = (const float*)d_in[4 + i];

  float* h_out = (float*)d_out;                     // [N,128]
  float* x_out = (float*)d_out + (size_t)N * 128;   // [N,3]

  // workspace carve
  float*    agg    = (float*)d_ws;                          // [N,128]
  unsigned* cnt    = (unsigned*)(agg + (size_t)N * 128);    // [N]
  unsigned* cursor = cnt + N;                               // [N]
  int*      sRowA  = (int*)(cursor + N);                    // [E]
  int*      sColA  = sRowA + E;                             // [E]
  float*    sRadA  = (float*)(sColA + E);                   // [E]
  float*    sEaA   = sRadA + E;                             // [E]
  unsigned short* hhi = (unsigned short*)(sEaA + E);        // [N,128]
  unsigned short* hlo = hhi + (size_t)N * 128;              // [N,128]
  unsigned short* wptr = hlo + (size_t)N * 128;

  WAll wa;
  auto addw = [&](int slot, const float* s, int K, int SW) {
    wa.m[slot].src = s; wa.m[slot].hi = wptr; wa.m[slot].lo = wptr + (size_t)K * 128;
    wa.m[slot].K = K; wa.m[slot].SW = SW;
    wptr += (size_t)2 * K * 128;
  };
  addw(0, P[0], 256, 258);  addw(1, P[2], 128, 128);   // g0 ew1, ew2
  addw(2, P[6], 256, 256);  addw(3, P[8], 128, 128);   // g0 nw1, nw2
  addw(4, P[10], 256, 258); addw(5, P[12], 128, 128);  // g1 ew1, ew2
  addw(6, P[16], 256, 256); addw(7, P[18], 128, 128);  // g1 nw1, nw2
  addw(8, P[20], 256, 258); addw(9, P[22], 128, 128);  // eq w1, w2

  hipMemcpyAsync(h_out, h_in, (size_t)N * 128 * sizeof(float),
                 hipMemcpyDeviceToDevice, stream);
  hipMemcpyAsync(x_out, x_in, (size_t)N * 3 * sizeof(float),
                 hipMemcpyDeviceToDevice, stream);

  // sort edges by row (counting sort); radial computed during scatter
  hipMemsetAsync(cnt, 0, (size_t)N * sizeof(unsigned), stream);
  hist_kernel<<<(E + 255) / 256, 256, 0, stream>>>(eidx, E, cnt);
  scan_kernel<<<1, 1024, 0, stream>>>(cnt, cursor, N);
  scatter_kernel<<<(E + 255) / 256, 256, 0, stream>>>(x_in, eidx, eattr, E,
      cursor, sRowA, sColA, sRadA, sEaA);

  wprep_kernel<<<dim3(128, 10), 256, 0, stream>>>(wa);

  const int n4 = N * 32;                 // N*128/4
  const int sg = (n4 + 255) / 256;
  const int eg = (E + 127) / 128;
  const int ng = (N + 127) / 128;
  const int smem0 = 32768 + 32768 + 2048;   // sH + stage + edge data
  const int smem1 = 32768 + 2048;

  for (int lyr = 0; lyr < 2; ++lyr) {
    const float* const* G = P + 10 * lyr;
    const WDesc* M = &wa.m[4 * lyr];
    split_kernel<<<sg, 256, 0, stream>>>(h_out, hhi, hlo, n4);
    hipMemsetAsync(agg, 0, (size_t)N * 128 * sizeof(float), stream);
    edge_mfma<0><<<eg, 256, smem0, stream>>>(hhi, hlo, sRowA, sColA, sRadA, sEaA, E,
        M[0].hi, M[0].lo, G[0], G[1], M[1].hi, M[1].lo, G[3],
        G[4], G[5], nullptr, agg);
    node_mfma<<<ng, 256, 0, stream>>>(h_out, hhi, hlo, agg, N,
        M[2].hi, M[2].lo, G[7], M[3].hi, M[3].lo, G[9]);
  }

  split_kernel<<<sg, 256, 0, stream>>>(h_out, hhi, hlo, n4);
  edge_mfma<1><<<eg, 256, smem1, stream>>>(hhi, hlo, sRowA, sColA, sRadA, sEaA, E,
      wa.m[8].hi, wa.m[8].lo, P[20], P[21], wa.m[9].hi, wa.m[9].lo, P[23],
      P[24], nullptr, x_in, x_out);
}